// Round 1
// 1936.487 us; speedup vs baseline: 1.1571x; 1.1571x over previous
//
#include <hip/hip_runtime.h>
#include <cstdint>

// TransformerClassification: B=32, S=1024, E=1024, FF=1024, OUT=2, 2 identical blocks.
// R3: 256x256 8-wave GEMM with 8-phase-style schedule (T2 swizzle + T3/T4 counted
// vmcnt + T5 setprio), per learn_hip m201 template. 128 KiB dbuf LDS, raw barriers.

#define AS1 __attribute__((address_space(1)))
#define AS3 __attribute__((address_space(3)))

typedef __attribute__((ext_vector_type(8))) short bf16x8;
typedef __attribute__((ext_vector_type(4))) float f32x4;
typedef __attribute__((ext_vector_type(4))) unsigned short us4;

__device__ __forceinline__ unsigned short f2bf(float f) {
  unsigned int u = __builtin_bit_cast(unsigned int, f);
  u += 0x7fffu + ((u >> 16) & 1u);          // round-to-nearest-even
  return (unsigned short)(u >> 16);
}
__device__ __forceinline__ float bf2f(unsigned short h) {
  return __builtin_bit_cast(float, (unsigned int)h << 16);
}

__device__ __forceinline__ void gload_lds16(const void* g, void* l) {
  auto gp = reinterpret_cast<AS1 unsigned int*>(reinterpret_cast<uintptr_t>(g));
  auto lp = reinterpret_cast<AS3 unsigned int*>(reinterpret_cast<uintptr_t>(l));
  __builtin_amdgcn_global_load_lds(gp, lp, 16, 0, 0);
}

enum { M_BF16 = 0, M_RELU = 1, M_QKV = 2, M_SCBF = 3, M_RESID = 4 };

// C = A (MxK bf16 rm) * B^T (B is NxK bf16 rm), batched via blockIdx.z.
// 256x256 tile, 512 threads = 8 waves (2M x 4N), per-wave 128x64 output
// (8x4 frags of 16x16x32). BK=64, 2-slot LDS dbuf, 4 phases per K-tile:
//   P1 quad(0,0): read aF[0..3]+bF[0..1] | stage B(g+1,h0) -> other slot
//   P2 quad(1,0): read aF[4..7]          | stage B(g+1,h1) -> other slot
//   P3 quad(1,1): read bF[2..3]          | stage A(g+2,h0) -> CURRENT slot (A reads done)
//   P4 quad(0,1): -                      | stage A(g+2,h1) -> CURRENT slot, vmcnt gate
// vmcnt(4) once per K-tile (3 half-tiles in flight); vmcnt(0) only in last 2 groups.
// LDS read swizzle: seg ^= (row&7); inverse applied on per-lane GLOBAL source so
// global_load_lds' linear lane*16B dest lands pre-swizzled (m173/m201 pattern).

#define MFMA_QUAD(qi, qj)                                                          \
  do {                                                                             \
    _Pragma("unroll") for (int i2 = 0; i2 < 4; ++i2) {                             \
      _Pragma("unroll") for (int j2 = 0; j2 < 2; ++j2) {                           \
        f32x4& c = acc[(qi) * 4 + i2][(qj) * 2 + j2];                              \
        c = __builtin_amdgcn_mfma_f32_16x16x32_bf16(aF[(qi) * 4 + i2][0],          \
                                                    bF[(qj) * 2 + j2][0], c, 0, 0, 0); \
        c = __builtin_amdgcn_mfma_f32_16x16x32_bf16(aF[(qi) * 4 + i2][1],          \
                                                    bF[(qj) * 2 + j2][1], c, 0, 0, 0); \
      }                                                                            \
    }                                                                              \
  } while (0)

template<int MODE>
__global__ __launch_bounds__(512, 2) void gemm_bt(
    const unsigned short* __restrict__ A, long long sAb,
    const unsigned short* __restrict__ B, long long sBb,
    const float* __restrict__ bias,
    const float* __restrict__ resid,
    float* __restrict__ outF,
    unsigned short* __restrict__ outBF,
    long long sOb, int N, int K, float scale)
{
  // 2 slots x (A[256][64] + B[256][64]) bf16 = 128 KiB
  __shared__ __align__(16) unsigned short lds[65536];
  const int t    = threadIdx.x;
  const int w    = t >> 6;
  const int lane = t & 63;
  const int quad = lane >> 4;
  const int l16  = lane & 15;
  const int l7   = l16 & 7;
  const int wm   = w >> 2;          // 0..1  (M half)
  const int wn   = w & 3;           // 0..3  (N quarter)
  const int bz   = blockIdx.z;
  const unsigned short* Ab = A + (long long)bz * sAb;
  const unsigned short* Bb = B + (long long)bz * sBb;
  const int m0 = blockIdx.y * 256;
  const int n0 = blockIdx.x * 256;

  // --- staging geometry: wave w covers rows {r*64 + w*8 + (lane>>3)} of a 128-row half.
  // Global source col is pre-swizzled so linear LDS landing == swizzled layout.
  const int sr8  = lane >> 3;                       // 0..7
  const int gseg = ((lane & 7) ^ sr8) << 3;         // swizzled 8-elem segment
  const unsigned short* aSrc = Ab + (long long)(m0 + w * 8 + sr8) * K + gseg;
  const unsigned short* bSrc = Bb + (long long)(n0 + w * 8 + sr8) * K + gseg;
  const int ldsW = w << 9;                          // w*512 elems

  // --- read geometry (row&7 == l16&7 for all frag rows)
  const int aOff = (wm * 128 + l16) * 64;
  const int bOff = 16384 + (wn * 64 + l16) * 64;
  const int seg0 = (quad ^ l7) << 3;                // kk=0 segment (swizzled)
  const int seg1 = ((quad + 4) ^ l7) << 3;          // kk=1 segment

  const int NG = K >> 6;                            // K-tiles (16 for K=1024)

  const f32x4 zero = {0.f, 0.f, 0.f, 0.f};
  f32x4 acc[8][4];
#pragma unroll
  for (int i = 0; i < 8; ++i)
#pragma unroll
    for (int j = 0; j < 4; ++j) acc[i][j] = zero;

  bf16x8 aF[8][2];
  bf16x8 bF[4][2];

#define STAGE_A(kt, h) do {                                                        \
    const unsigned short* _s = aSrc + (long long)(h) * 128 * K + (kt) * 64;        \
    unsigned short* _d = &lds[(((kt) & 1) << 15) + ((h) << 13) + ldsW];            \
    gload_lds16(_s, _d);                                                           \
    gload_lds16(_s + 64 * (long long)K, _d + 4096);                                \
  } while (0)
#define STAGE_B(kt, h) do {                                                        \
    const unsigned short* _s = bSrc + (long long)(h) * 128 * K + (kt) * 64;        \
    unsigned short* _d = &lds[(((kt) & 1) << 15) + 16384 + ((h) << 13) + ldsW];    \
    gload_lds16(_s, _d);                                                           \
    gload_lds16(_s + 64 * (long long)K, _d + 4096);                                \
  } while (0)

  // ---- prologue: Kt0 all 4 half-tiles, Kt1 A-halves (order matters for vmcnt)
  STAGE_A(0, 0); STAGE_A(0, 1); STAGE_B(0, 0); STAGE_B(0, 1);
  STAGE_A(1, 0); STAGE_A(1, 1);
  asm volatile("s_waitcnt vmcnt(4)" ::: "memory");   // Kt0 landed; Kt1 A in flight
  __builtin_amdgcn_s_barrier();
  asm volatile("" ::: "memory");

#pragma unroll 1
  for (int g = 0; g < NG; ++g) {
    const unsigned short* As = &lds[(g & 1) << 15];

    // ---------------- P1: quad(0,0)
#pragma unroll
    for (int i2 = 0; i2 < 4; ++i2) {
      aF[i2][0] = *(const bf16x8*)&As[aOff + i2 * 1024 + seg0];
      aF[i2][1] = *(const bf16x8*)&As[aOff + i2 * 1024 + seg1];
    }
#pragma unroll
    for (int j2 = 0; j2 < 2; ++j2) {
      bF[j2][0] = *(const bf16x8*)&As[bOff + j2 * 1024 + seg0];
      bF[j2][1] = *(const bf16x8*)&As[bOff + j2 * 1024 + seg1];
    }
    if (g + 1 < NG) STAGE_B(g + 1, 0);
    __builtin_amdgcn_s_barrier();
    asm volatile("s_waitcnt lgkmcnt(0)" ::: "memory");
    __builtin_amdgcn_s_setprio(1);
    MFMA_QUAD(0, 0);
    __builtin_amdgcn_s_setprio(0);
    __builtin_amdgcn_s_barrier();
    asm volatile("" ::: "memory");

    // ---------------- P2: quad(1,0)
#pragma unroll
    for (int i2 = 0; i2 < 4; ++i2) {
      aF[4 + i2][0] = *(const bf16x8*)&As[aOff + (4 + i2) * 1024 + seg0];
      aF[4 + i2][1] = *(const bf16x8*)&As[aOff + (4 + i2) * 1024 + seg1];
    }
    if (g + 1 < NG) STAGE_B(g + 1, 1);
    __builtin_amdgcn_s_barrier();
    asm volatile("s_waitcnt lgkmcnt(0)" ::: "memory");
    __builtin_amdgcn_s_setprio(1);
    MFMA_QUAD(1, 0);
    __builtin_amdgcn_s_setprio(0);
    __builtin_amdgcn_s_barrier();
    asm volatile("" ::: "memory");

    // ---------------- P3: quad(1,1)   (all A reads of this slot are done)
#pragma unroll
    for (int j2 = 0; j2 < 2; ++j2) {
      bF[2 + j2][0] = *(const bf16x8*)&As[bOff + (2 + j2) * 1024 + seg0];
      bF[2 + j2][1] = *(const bf16x8*)&As[bOff + (2 + j2) * 1024 + seg1];
    }
    if (g + 2 < NG) STAGE_A(g + 2, 0);
    __builtin_amdgcn_s_barrier();
    asm volatile("s_waitcnt lgkmcnt(0)" ::: "memory");
    __builtin_amdgcn_s_setprio(1);
    MFMA_QUAD(1, 1);
    __builtin_amdgcn_s_setprio(0);
    __builtin_amdgcn_s_barrier();
    asm volatile("" ::: "memory");

    // ---------------- P4: quad(0,1)
    if (g + 2 < NG) STAGE_A(g + 2, 1);
    if (g >= NG - 2) {
      asm volatile("s_waitcnt vmcnt(0)" ::: "memory");   // tail: full drain
    } else {
      asm volatile("s_waitcnt vmcnt(4)" ::: "memory");   // allow Kt(g+2) A-halves in flight
    }
    __builtin_amdgcn_s_barrier();
    __builtin_amdgcn_s_setprio(1);
    MFMA_QUAD(0, 1);
    __builtin_amdgcn_s_setprio(0);
    __builtin_amdgcn_s_barrier();
    asm volatile("" ::: "memory");
  }

#undef STAGE_A
#undef STAGE_B

  // Epilogue. C/D layout: col = lane&15, row = quad*4 + reg
#pragma unroll
  for (int i = 0; i < 8; ++i) {
    const int mt = m0 + wm * 128 + i * 16 + quad * 4;
#pragma unroll
    for (int j = 0; j < 4; ++j) {
      const int nt = n0 + wn * 64 + j * 16 + l16;
      f32x4 d = acc[i][j];
      if (MODE == M_BF16 || MODE == M_RELU) {
        const float bv = bias ? bias[nt] : 0.0f;
#pragma unroll
        for (int r = 0; r < 4; ++r) {
          float v = d[r] + bv;
          if (MODE == M_RELU) v = fmaxf(v, 0.0f);
          outBF[(long long)bz * sOb + (long long)(mt + r) * N + nt] = f2bf(v);
        }
      } else if (MODE == M_SCBF) {
#pragma unroll
        for (int r = 0; r < 4; ++r)
          outBF[(long long)bz * sOb + (long long)(mt + r) * N + nt] = f2bf(d[r] * scale);
      } else if (MODE == M_RESID) {
        const float bv = bias[nt];
#pragma unroll
        for (int r = 0; r < 4; ++r) {
          const long long idx = (long long)(mt + r) * N + nt;
          outF[idx] = resid[idx] + d[r] + bv;
        }
      } else if (MODE == M_QKV) {
        // N=3072 packed: seg 0 -> Q [32768,1024], seg 1 -> K [32768,1024],
        // seg 2 -> V transposed per batch: vT[b][d][s].
        const int seg = n0 >> 10;         // block-uniform (1024 % 256 == 0)
        const int ntl = nt - (seg << 10);
        const float bv = bias[nt];
        if (seg < 2) {
          unsigned short* dst = outBF + (long long)seg * 33554432LL;
#pragma unroll
          for (int r = 0; r < 4; ++r)
            dst[(long long)(mt + r) * 1024 + ntl] = f2bf(d[r] + bv);
        } else {
          unsigned short* dst = outBF + 2LL * 33554432LL;
          us4 pk;
#pragma unroll
          for (int r = 0; r < 4; ++r) pk[r] = f2bf(d[r] + bv);
          const int b = mt >> 10;
          const int s = mt & 1023;
          *(us4*)&dst[(long long)b * 1048576 + (long long)ntl * 1024 + s] = pk;
        }
      }
    }
  }
}

// LayerNorm over rows of 1024. EMBED=1: v = 32*x + pe written to x1out; else read xin.
template<int EMBED>
__global__ __launch_bounds__(256) void ln_kernel(
    const float* __restrict__ xin, const float* __restrict__ pe,
    float* __restrict__ x1out,
    const float* __restrict__ g, const float* __restrict__ bb,
    unsigned short* __restrict__ hout)
{
  __shared__ float red[8];
  const long long row = blockIdx.x;
  const int t = threadIdx.x, lane = t & 63, w = t >> 6;
  float4 v = *(const float4*)(xin + row * 1024 + t * 4);
  if (EMBED) {
    const int s = (int)(row & 1023);
    float4 p = *(const float4*)(pe + (long long)s * 1024 + t * 4);
    v.x = 32.0f * v.x + p.x;
    v.y = 32.0f * v.y + p.y;
    v.z = 32.0f * v.z + p.z;
    v.w = 32.0f * v.w + p.w;
    *(float4*)(x1out + row * 1024 + t * 4) = v;
  }
  float sum = v.x + v.y + v.z + v.w;
  float sq  = v.x * v.x + v.y * v.y + v.z * v.z + v.w * v.w;
#pragma unroll
  for (int off = 32; off > 0; off >>= 1) {
    sum += __shfl_down(sum, off, 64);
    sq  += __shfl_down(sq,  off, 64);
  }
  if (lane == 0) { red[w] = sum; red[4 + w] = sq; }
  __syncthreads();
  sum = red[0] + red[1] + red[2] + red[3];
  sq  = red[4] + red[5] + red[6] + red[7];
  const float mu  = sum * (1.0f / 1024.0f);
  const float var = sq * (1.0f / 1024.0f) - mu * mu;
  const float rs  = rsqrtf(var + 1e-5f);
  float4 gg = *(const float4*)(g + t * 4);
  float4 bv = *(const float4*)(bb + t * 4);
  us4 h;
  h[0] = f2bf((v.x - mu) * rs * gg.x + bv.x);
  h[1] = f2bf((v.y - mu) * rs * gg.y + bv.y);
  h[2] = f2bf((v.z - mu) * rs * gg.z + bv.z);
  h[3] = f2bf((v.w - mu) * rs * gg.w + bv.w);
  *(us4*)(hout + row * 1024 + t * 4) = h;
}

// Softmax over rows of 1024: reads bf16 scores, writes fp32 w (d_out) + bf16 w.
__global__ __launch_bounds__(256) void softmax_kernel(
    const unsigned short* __restrict__ sbf,
    float* __restrict__ wout, unsigned short* __restrict__ wbf)
{
  __shared__ float red[8];
  const long long row = blockIdx.x;
  const int t = threadIdx.x, lane = t & 63, w = t >> 6;
  us4 sv = *(const us4*)(sbf + row * 1024 + t * 4);
  float4 v;
  v.x = bf2f(sv[0]); v.y = bf2f(sv[1]); v.z = bf2f(sv[2]); v.w = bf2f(sv[3]);
  float mx = fmaxf(fmaxf(v.x, v.y), fmaxf(v.z, v.w));
#pragma unroll
  for (int off = 32; off > 0; off >>= 1) mx = fmaxf(mx, __shfl_down(mx, off, 64));
  if (lane == 0) red[w] = mx;
  __syncthreads();
  mx = fmaxf(fmaxf(red[0], red[1]), fmaxf(red[2], red[3]));
  __syncthreads();
  const float e0 = __expf(v.x - mx), e1 = __expf(v.y - mx);
  const float e2 = __expf(v.z - mx), e3 = __expf(v.w - mx);
  float s = e0 + e1 + e2 + e3;
#pragma unroll
  for (int off = 32; off > 0; off >>= 1) s += __shfl_down(s, off, 64);
  if (lane == 0) red[w] = s;
  __syncthreads();
  s = red[0] + red[1] + red[2] + red[3];
  const float inv = 1.0f / s;
  float4 o; o.x = e0 * inv; o.y = e1 * inv; o.z = e2 * inv; o.w = e3 * inv;
  *(float4*)(wout + row * 1024 + t * 4) = o;
  us4 ob;
  ob[0] = f2bf(o.x); ob[1] = f2bf(o.y); ob[2] = f2bf(o.z); ob[3] = f2bf(o.w);
  *(us4*)(wbf + row * 1024 + t * 4) = ob;
}

// One prep kernel: bf16-convert all 6 weights (QKV packed [3072,1024]) + pack QKV bias.
__global__ __launch_bounds__(256) void prep_kernel(
    const float* __restrict__ Wq, const float* __restrict__ Wk, const float* __restrict__ Wv,
    const float* __restrict__ Wo, const float* __restrict__ W1, const float* __restrict__ W2,
    const float* __restrict__ bq, const float* __restrict__ bk, const float* __restrict__ bv,
    unsigned short* __restrict__ qkvw, unsigned short* __restrict__ Wo_bf,
    unsigned short* __restrict__ W1_bf, unsigned short* __restrict__ W2_bf,
    float* __restrict__ qkvb)
{
  const int y = blockIdx.y;
  const long long i = blockIdx.x * 256 + threadIdx.x;   // quad index, < 262144
  if (y == 6) {
    if (i < 768) {
      const float* src = (i < 256) ? bq : (i < 512) ? bk : bv;
      float4 v = *(const float4*)(src + (i & 255) * 4);
      *(float4*)(qkvb + i * 4) = v;
    }
    return;
  }
  const float* src;
  unsigned short* dst;
  switch (y) {
    case 0: src = Wq; dst = qkvw;            break;
    case 1: src = Wk; dst = qkvw + 1048576;  break;
    case 2: src = Wv; dst = qkvw + 2097152;  break;
    case 3: src = Wo; dst = Wo_bf;           break;
    case 4: src = W1; dst = W1_bf;           break;
    default: src = W2; dst = W2_bf;          break;
  }
  float4 v = *(const float4*)(src + i * 4);
  us4 o;
  o[0] = f2bf(v.x); o[1] = f2bf(v.y); o[2] = f2bf(v.z); o[3] = f2bf(v.w);
  *(us4*)(dst + i * 4) = o;
}

// logits[b,o] = x[b, s=0, :] . Wc[o,:] + bc[o]; 64 blocks, fp32.
__global__ __launch_bounds__(256) void logits_kernel(
    const float* __restrict__ x, const float* __restrict__ Wc,
    const float* __restrict__ bc, float* __restrict__ out)
{
  __shared__ float red[4];
  const int blk = blockIdx.x;           // b*2 + o
  const int b = blk >> 1, o = blk & 1;
  const int t = threadIdx.x, lane = t & 63, w = t >> 6;
  const float* xr = x + (long long)b * 1048576;
  const float* wr = Wc + o * 1024;
  float4 xv = *(const float4*)(xr + t * 4);
  float4 wv = *(const float4*)(wr + t * 4);
  float s = xv.x * wv.x + xv.y * wv.y + xv.z * wv.z + xv.w * wv.w;
#pragma unroll
  for (int off = 32; off > 0; off >>= 1) s += __shfl_down(s, off, 64);
  if (lane == 0) red[w] = s;
  __syncthreads();
  if (t == 0) out[blk] = red[0] + red[1] + red[2] + red[3] + bc[o];
}

extern "C" void kernel_launch(void* const* d_in, const int* in_sizes, int n_in,
                              void* d_out, int out_size, void* d_ws, size_t ws_size,
                              hipStream_t stream)
{
  const float* x    = (const float*)d_in[0];
  const float* pe   = (const float*)d_in[1];
  const float* ln1g = (const float*)d_in[2];
  const float* ln1b = (const float*)d_in[3];
  const float* Wq   = (const float*)d_in[4];
  const float* bq   = (const float*)d_in[5];
  const float* Wk   = (const float*)d_in[6];
  const float* bk   = (const float*)d_in[7];
  const float* Wv   = (const float*)d_in[8];
  const float* bv   = (const float*)d_in[9];
  const float* Wo   = (const float*)d_in[10];
  const float* bo   = (const float*)d_in[11];
  const float* ln2g = (const float*)d_in[12];
  const float* ln2b = (const float*)d_in[13];
  const float* W1   = (const float*)d_in[14];
  const float* b1   = (const float*)d_in[15];
  const float* W2   = (const float*)d_in[16];
  const float* b2   = (const float*)d_in[17];
  const float* Wc   = (const float*)d_in[18];
  const float* bc   = (const float*)d_in[19];
  float* out = (float*)d_out;

  // Workspace layout (~400 MiB):
  //   xbuf   128 MiB fp32 residual stream
  //   h_bf    64 MiB (LN out; reused as bf16 scores scratch)
  //   q_bf    64 MiB (QKV seg0; reused as attn out)
  //   k_bf    64 MiB (QKV seg1; reused as bf16 softmax weights)
  //   vT_bf   64 MiB (QKV seg2, transposed; reused as ff1)
  //   weights: QKV packed 6 MiB + Wo/W1/W2 2 MiB each + qkvb 12 KiB
  char* ws = (char*)d_ws;
  float*          xbuf  = (float*)ws;
  unsigned short* h_bf  = (unsigned short*)(ws + 134217728LL);
  unsigned short* q_bf  = (unsigned short*)(ws + 134217728LL + 1 * 67108864LL);
  unsigned short* k_bf  = (unsigned short*)(ws + 134217728LL + 2 * 67108864LL);
  unsigned short* vT_bf = (unsigned short*)(ws + 134217728LL + 3 * 67108864LL);
  unsigned short* wts   = (unsigned short*)(ws + 134217728LL + 4 * 67108864LL);
  unsigned short* QKV_bf = wts;                       // [3072,1024]
  unsigned short* Wo_bf  = wts + 3LL * 1048576;
  unsigned short* W1_bf  = wts + 4LL * 1048576;
  unsigned short* W2_bf  = wts + 5LL * 1048576;
  float*          qkvb   = (float*)(wts + 6LL * 1048576);  // [3072]
  unsigned short* sc_bf   = h_bf;
  unsigned short* w_bf    = k_bf;
  unsigned short* attn_bf = q_bf;
  unsigned short* ff1_bf  = vT_bf;

  const dim3 blk(256);
  const dim3 blkG(512);
  prep_kernel<<<dim3(1024, 7), blk, 0, stream>>>(Wq, Wk, Wv, Wo, W1, W2, bq, bk, bv,
                                                 QKV_bf, Wo_bf, W1_bf, W2_bf, qkvb);

  const dim3 gQKV(12, 128, 1);   // N=3072, M=32768, 256^2 tiles
  const dim3 gProj(4, 128, 1);   // N=1024, M=32768
  const dim3 gAttn(4, 4, 32);    // N=M=1024, batch=32

  for (int blkI = 0; blkI < 2; ++blkI) {
    float* wslot = out + 64 + (long long)blkI * 33554432LL;

    if (blkI == 0)
      ln_kernel<1><<<32768, blk, 0, stream>>>(x, pe, xbuf, ln1g, ln1b, h_bf);
    else
      ln_kernel<0><<<32768, blk, 0, stream>>>(xbuf, nullptr, nullptr, ln1g, ln1b, h_bf);

    gemm_bt<M_QKV><<<gQKV, blkG, 0, stream>>>(h_bf, 0, QKV_bf, 0, qkvb, nullptr,
                                              nullptr, q_bf, 0, 3072, 1024, 1.0f);

    gemm_bt<M_SCBF><<<gAttn, blkG, 0, stream>>>(q_bf, 1048576, k_bf, 1048576, nullptr,
                                                nullptr, nullptr, sc_bf, 1048576,
                                                1024, 1024, 0.03125f);
    softmax_kernel<<<32768, blk, 0, stream>>>(sc_bf, wslot, w_bf);

    gemm_bt<M_BF16><<<gAttn, blkG, 0, stream>>>(w_bf, 1048576, vT_bf, 1048576, nullptr,
                                                nullptr, nullptr, attn_bf, 1048576,
                                                1024, 1024, 1.0f);
    gemm_bt<M_RESID><<<gProj, blkG, 0, stream>>>(attn_bf, 0, Wo_bf, 0, bo, xbuf,
                                                 xbuf, nullptr, 0, 1024, 1024, 1.0f);

    ln_kernel<0><<<32768, blk, 0, stream>>>(xbuf, nullptr, nullptr, ln2g, ln2b, h_bf);
    gemm_bt<M_RELU><<<gProj, blkG, 0, stream>>>(h_bf, 0, W1_bf, 0, b1, nullptr,
                                                nullptr, ff1_bf, 0, 1024, 1024, 1.0f);
    gemm_bt<M_RESID><<<gProj, blkG, 0, stream>>>(ff1_bf, 0, W2_bf, 0, b2, xbuf,
                                                 xbuf, nullptr, 0, 1024, 1024, 1.0f);
  }

  logits_kernel<<<64, blk, 0, stream>>>(xbuf, Wc, bc, out);
  (void)in_sizes; (void)n_in; (void)out_size; (void)ws_size;
}